// Round 12
// baseline (932.159 us; speedup 1.0000x reference)
//
#include <hip/hip_runtime.h>

#define E_TOTAL 1600000
#define NN 100000
#define D 128      // node dim
#define ED 32      // edge dim
#define H 256      // hidden dim

typedef __attribute__((ext_vector_type(8))) short s16x8;   // 8 bf16 (one MFMA A/B frag)
typedef __attribute__((ext_vector_type(4))) short s16x4;
typedef __attribute__((ext_vector_type(4))) float f32x4;

#define MFMA(a, b, c) __builtin_amdgcn_mfma_f32_16x16x32_bf16((a), (b), (c), 0, 0, 0)

__device__ __forceinline__ short f2bf(float f) {
    unsigned u = __builtin_bit_cast(unsigned, f);
    u += 0x7fffu + ((u >> 16) & 1u);   // round-to-nearest-even
    return (short)(u >> 16);
}
__device__ __forceinline__ float bf2f(short s) {
    return __builtin_bit_cast(float, ((unsigned)(unsigned short)s) << 16);
}

// async global->LDS, 16B per lane; LDS dest is wave-uniform base (HW adds lane*16)
__device__ __forceinline__ void gll16(const void* g, void* l) {
    __builtin_amdgcn_global_load_lds(
        (const __attribute__((address_space(1))) void*)g,
        (__attribute__((address_space(3))) void*)l, 16, 0, 0);
}

// ---- fused prep: x->bf16 cvt | dst histogram | weight swizzles ----
__device__ __forceinline__ void swz_one(const float* __restrict__ W,
                                        short* __restrict__ out,
                                        int K, int N, int idx) {
    int j    = idx & 7;
    int lane = (idx >> 3) & 63;
    int rest = idx >> 9;
    int NT   = N >> 4;
    int nt   = rest % NT;
    int t    = rest / NT;
    int k    = t * 32 + (lane >> 4) * 8 + j;
    int col  = nt * 16 + (lane & 15);
    out[idx] = f2bf((k < K) ? W[k * N + col] : 0.f);
}

// K-permuted variant for layer-2 weights: physical k-slot p holds logical row
// pi(p) = (p>>6)*64 + (p&3)*16 + ((p>>2)&15)  — matches the quad h layout, so
// sum_p h_phys[e][p] * Wp[p][oc] == sum_c h[e][c] * W[c][oc]  (K = 256 exact).
__device__ __forceinline__ void swz_kp(const float* __restrict__ W,
                                       short* __restrict__ out, int N, int idx) {
    int j    = idx & 7;
    int lane = (idx >> 3) & 63;
    int rest = idx >> 9;
    int NT   = N >> 4;
    int nt   = rest % NT;
    int t    = rest / NT;
    int p    = t * 32 + (lane >> 4) * 8 + j;
    int k    = (p >> 6) * 64 + (p & 3) * 16 + ((p >> 2) & 15);
    int col  = nt * 16 + (lane & 15);
    out[idx] = f2bf(W[k * N + col]);
}

__global__ void k_prep(const float* __restrict__ x, short* __restrict__ xb,
                       const int* __restrict__ ei, int* __restrict__ cnt,
                       const float* __restrict__ mW1, short* __restrict__ W1s,
                       const float* __restrict__ mW2, short* __restrict__ W2s,
                       const float* __restrict__ uW1, short* __restrict__ U1s,
                       const float* __restrict__ uW2, short* __restrict__ U2s) {
    const int b = blockIdx.x;
    if (b < 12500) {                       // cvt x -> bf16
        int i = (b * 256 + threadIdx.x) * 4;
        if (i >= NN * D) return;
        f32x4 v = *(const f32x4*)(x + i);
        s16x4 o;
        o[0] = f2bf(v[0]); o[1] = f2bf(v[1]); o[2] = f2bf(v[2]); o[3] = f2bf(v[3]);
        *(s16x4*)(xb + i) = o;
    } else if (b < 18750) {                // dst histogram
        int e = (b - 12500) * 256 + threadIdx.x;
        if (e < E_TOTAL) atomicAdd(&cnt[ei[E_TOTAL + e]], 1);
    } else {                               // 4 weight swizzles (W2/U2 K-permuted)
        int idx = (b - 18750) * 256 + threadIdx.x;
        if (idx < 81920) { swz_one(mW1, W1s, 289, 256, idx); return; }
        idx -= 81920;
        if (idx < 32768) { swz_kp(mW2, W2s, 128, idx); return; }
        idx -= 32768;
        if (idx < 65536) { swz_one(uW1, U1s, 256, 256, idx); return; }
        idx -= 65536;
        if (idx < 32768) { swz_kp(uW2, U2s, 128, idx); }
    }
}

// ---- single-kernel scan (decoupled lookback) + fused agg init ----
// chain[b]: bits 32..63 = state (1=aggregate, 2=prefix), low 32 = value.
// After the scan, the block also writes agg[node][c] = deg(node)*b2[c]
// (deg = each thread's original count, kept in-register).
__global__ void k_scanc(int* __restrict__ cnt, unsigned long long* __restrict__ chain,
                        const float* __restrict__ b2, float* __restrict__ agg,
                        int n) {
    __shared__ int wsum[16];
    __shared__ int woff[16];
    __shared__ int carry_s;
    __shared__ int deg_s[1024];
    const int tid = threadIdx.x, lane = tid & 63, wv = tid >> 6;
    int i = blockIdx.x * 1024 + tid;
    int v = (i < n) ? cnt[i] : 0;
    int s = v;
#pragma unroll
    for (int off = 1; off < 64; off <<= 1) {
        int u = __shfl_up(s, off, 64);
        if (lane >= off) s += u;
    }
    if (lane == 63) wsum[wv] = s;
    __syncthreads();
    if (wv == 0 && lane < 16) {
        int t = wsum[lane];
        int sc = t;
#pragma unroll
        for (int off = 1; off < 16; off <<= 1) {
            int u = __shfl_up(sc, off, 16);
            if (lane >= off) sc += u;
        }
        woff[lane] = sc - t;
    }
    __syncthreads();
    int excl = (s - v) + woff[wv];
    if (tid == 1023) {
        int btot = excl + v;
        __hip_atomic_store(&chain[blockIdx.x], (1ull << 32) | (unsigned)btot,
                           __ATOMIC_RELAXED, __HIP_MEMORY_SCOPE_AGENT);
        int pfx = 0;
        for (int j = (int)blockIdx.x - 1; j >= 0; --j) {
            unsigned long long e;
            do {
                e = __hip_atomic_load(&chain[j], __ATOMIC_RELAXED,
                                      __HIP_MEMORY_SCOPE_AGENT);
            } while ((e >> 32) == 0);
            pfx += (int)(unsigned)e;
            if ((e >> 32) == 2) break;
        }
        __hip_atomic_store(&chain[blockIdx.x], (2ull << 32) | (unsigned)(pfx + btot),
                           __ATOMIC_RELAXED, __HIP_MEMORY_SCOPE_AGENT);
        carry_s = pfx;
    }
    deg_s[tid] = v;
    __syncthreads();
    if (i < n) cnt[i] = excl + carry_s;

    // fused agg init: block covers nodes [base, base+1024); coalesced f32x4 writes
    const int base = blockIdx.x * 1024;
#pragma unroll
    for (int it = 0; it < 32; it++) {
        int idx  = it * 1024 + tid;        // node-local*32 + 16B-slot
        int node = base + (idx >> 5);
        if (node < n) {
            float deg = (float)deg_s[idx >> 5];
            int c = (idx & 31) * 4;
            f32x4 bv = *(const f32x4*)(b2 + c);
            f32x4 o;
#pragma unroll
            for (int j = 0; j < 4; j++) o[j] = deg * bv[j];
            *(f32x4*)(agg + (long)node * D + c) = o;
        }
    }
}

// ---- sort prep: scatter edges into dst-sorted order ----
__global__ void k_perm(const int* __restrict__ ei, int* __restrict__ cursor,
                       int* __restrict__ perm, int2* __restrict__ srcdst) {
    int e = blockIdx.x * blockDim.x + threadIdx.x;
    if (e >= E_TOTAL) return;
    int s = ei[e], d = ei[E_TOTAL + e];
    int pos = atomicAdd(&cursor[d], 1);
    perm[pos] = e;
    srcdst[pos] = make_int2(s, d);
}

// ---- per-node precompute: ys = x @ W1[:128,:] + b1, yd = x @ W1[128:256,:] ----
// Quad C-fragment layout: y[node*256 + (cg*16+m)*4 + n] = col (cg*64+n*16+m).
__global__ __launch_bounds__(512, 4)
void k_pre(const short* __restrict__ xb, const short* __restrict__ W1s,
           const float* __restrict__ b1, short* __restrict__ ys,
           short* __restrict__ yd) {
    __shared__ char smem[32768];     // x: 4 chunks x [128 rows][64B], swizzled
    const int tid  = threadIdx.x;
    const int lane = tid & 63;
    const int w    = tid >> 6;
    const int eh   = w >> 2;
    const int cg   = w & 3;
    const int m    = lane & 15;
    const int q    = lane >> 4;
    const int r0   = blockIdx.x * 128;

    {
        int rowl = w * 16 + (lane >> 2);
        int grow = r0 + rowl;
        int gc   = grow < NN ? grow : 0;
        int kqs  = (lane & 3) ^ ((lane >> 3) & 3);
        const char* gx = (const char*)xb + (long)gc * 256 + kqs * 16;
#pragma unroll
        for (int t = 0; t < 4; t++)
            gll16(gx + t * 64, smem + t * 8192 + w * 1024);
    }
    __syncthreads();

    const int rdoff = m * 64 + ((q ^ ((m >> 1) & 3)) << 4);

    float b1c[4];
#pragma unroll
    for (int n = 0; n < 4; n++) b1c[n] = b1[cg * 64 + n * 16 + m];

#pragma unroll
    for (int pass = 0; pass < 2; pass++) {   // 0: ys (W1 chunks 0..3), 1: yd (4..7)
        f32x4 acc[4][4];
#pragma unroll
        for (int mt = 0; mt < 4; mt++)
#pragma unroll
            for (int n = 0; n < 4; n++) acc[mt][n] = (f32x4){0.f, 0.f, 0.f, 0.f};
#pragma unroll
        for (int t = 0; t < 4; t++) {
            s16x8 b[4];
            const short* bw = W1s + ((pass * 4 + t) * 16 + cg * 4) * 512 + lane * 8;
#pragma unroll
            for (int n = 0; n < 4; n++) b[n] = *(const s16x8*)(bw + n * 512);
#pragma unroll
            for (int mt = 0; mt < 4; mt++) {
                s16x8 a = *(const s16x8*)(smem + t * 8192 + (eh * 4 + mt) * 1024 + rdoff);
#pragma unroll
                for (int n = 0; n < 4; n++) acc[mt][n] = MFMA(a, b[n], acc[mt][n]);
            }
        }
        short* out = pass ? yd : ys;
#pragma unroll
        for (int mt = 0; mt < 4; mt++)
#pragma unroll
            for (int r = 0; r < 4; r++) {
                int grow = r0 + eh * 64 + mt * 16 + q * 4 + r;
                if (grow < NN) {
                    s16x4 o;
#pragma unroll
                    for (int n = 0; n < 4; n++)
                        o[n] = f2bf(acc[mt][n][r] + (pass ? 0.f : b1c[n]));
                    *(s16x4*)(out + (long)grow * 256 + (cg * 16 + m) * 4) = o;
                }
            }
    }
}

// ---- edge MLP + segment-reduced scatter-add: quad-h layout ----
// h stored as h[e][p], p = (cg*16+m)*4+n (quad C-order), 16B slots XOR'd by
// (e&31). h-write = 16 ds_write_b64/thread (was 64 b16). Layer-2 A-fragments
// read physical k-slots directly; W2s rows are K-permuted to match (swz_kp).
__global__ __launch_bounds__(512, 4)
void k_edge(const int* __restrict__ perm, const int2* __restrict__ srcdst,
            const short* __restrict__ ys, const short* __restrict__ yd,
            const float* __restrict__ eattr, const float* __restrict__ cong,
            const short* __restrict__ W1s, const short* __restrict__ W2s,
            float* __restrict__ agg) {
    __shared__ char smem[73728];     // eattr chunk [0,8K); h quad [8K,72K); mbuf aliases
    __shared__ int   dst_s[128];
    __shared__ int   src_s[128];
    __shared__ short cong_s[128];

    const int tid  = threadIdx.x;
    const int lane = tid & 63;
    const int w    = tid >> 6;       // wave 0..7
    const int eh   = w >> 2;         // edge half: rows [eh*64, +64)
    const int cg   = w & 3;          // col group: l1 cols [cg*64,+64), l2 [cg*32,+32)
    const int m    = lane & 15;
    const int q    = lane >> 4;
    const int p0b  = blockIdx.x * 128;

    // ---- stage eattr chunk (swizzled) + edge metadata ----
    {
        int edge = w * 16 + (lane >> 2);
        int kqs  = (lane & 3) ^ ((lane >> 3) & 3);
        int ea = perm[p0b + edge];
        const float* ge = eattr + (long)ea * ED + kqs * 8;
        f32x4 e0 = *(const f32x4*)ge, e1 = *(const f32x4*)(ge + 4);
        s16x8 ev;
#pragma unroll
        for (int j = 0; j < 4; j++) { ev[j] = f2bf(e0[j]); ev[4 + j] = f2bf(e1[j]); }
        *(s16x8*)(smem + w * 1024 + lane * 16) = ev;
        if (tid < 128) {
            int2 sd2 = srcdst[p0b + tid];
            dst_s[tid]  = sd2.y;
            src_s[tid]  = sd2.x;
            cong_s[tid] = f2bf(cong[sd2.x]);
        }
    }
    __syncthreads();

    const int rdoff = m * 64 + ((q ^ ((m >> 1) & 3)) << 4);   // conflict-free A-read

    // ---- layer 1: eattr (W1 chunk 8) + cong (chunk 9); 64 edges x 64 cols ----
    f32x4 acc[4][4];
#pragma unroll
    for (int mt = 0; mt < 4; mt++)
#pragma unroll
        for (int n = 0; n < 4; n++) acc[mt][n] = (f32x4){0.f, 0.f, 0.f, 0.f};

    {   // eattr k-chunk
        s16x8 b[4];
        const short* bw = W1s + (8 * 16 + cg * 4) * 512 + lane * 8;
#pragma unroll
        for (int n = 0; n < 4; n++) b[n] = *(const s16x8*)(bw + n * 512);
#pragma unroll
        for (int mt = 0; mt < 4; mt++) {
            s16x8 a = *(const s16x8*)(smem + (eh * 4 + mt) * 1024 + rdoff);
#pragma unroll
            for (int n = 0; n < 4; n++) acc[mt][n] = MFMA(a, b[n], acc[mt][n]);
        }
    }
    {   // congestion feature (k=288, W1 chunk 9)
        s16x8 b[4];
        const short* bw = W1s + (9 * 16 + cg * 4) * 512 + lane * 8;
#pragma unroll
        for (int n = 0; n < 4; n++) b[n] = *(const s16x8*)(bw + n * 512);
#pragma unroll
        for (int mt = 0; mt < 4; mt++) {
            s16x8 a = (s16x8){0, 0, 0, 0, 0, 0, 0, 0};
            short cv = cong_s[eh * 64 + mt * 16 + m];
            a[0] = (q == 0) ? cv : (short)0;
#pragma unroll
            for (int n = 0; n < 4; n++) acc[mt][n] = MFMA(a, b[n], acc[mt][n]);
        }
    }

    // ---- h-write: acc + ys[src] + yd[dst], relu -> quad layout, b64 stores ----
    {
        char* hbase = smem + 8192;
        const int qoff = (cg * 16 + m) * 4;
        const int s0   = (cg * 16 + m) >> 1;      // 16B slot index (pre-XOR)
        const int half = (m & 1) * 8;             // byte offset within slot
#pragma unroll
        for (int mt = 0; mt < 4; mt++) {
            s16x4 ysv[4], ydv[4];
#pragma unroll
            for (int r = 0; r < 4; r++) {          // batched loads, 4-deep pipeline
                int e = eh * 64 + mt * 16 + q * 4 + r;
                ysv[r] = *(const s16x4*)(ys + (long)src_s[e] * 256 + qoff);
                ydv[r] = *(const s16x4*)(yd + (long)dst_s[e] * 256 + qoff);
            }
#pragma unroll
            for (int r = 0; r < 4; r++) {
                int e = eh * 64 + mt * 16 + q * 4 + r;
                int sl = s0 ^ (e & 31);
                s16x4 o;
#pragma unroll
                for (int n = 0; n < 4; n++) {
                    float v = acc[mt][n][r] + bf2f(ysv[r][n]) + bf2f(ydv[r][n]);
                    o[n] = f2bf(v > 0.f ? v : 0.f);
                }
                *(s16x4*)(hbase + e * 512 + sl * 16 + half) = o;
            }
        }
    }
    __syncthreads();

    // ---- layer 2: K=256 (physical k-slots); 64 edges x 32 cols per wave ----
    f32x4 acc2[4][2];
#pragma unroll
    for (int mt = 0; mt < 4; mt++) {
        acc2[mt][0] = (f32x4){0.f, 0.f, 0.f, 0.f};
        acc2[mt][1] = (f32x4){0.f, 0.f, 0.f, 0.f};
    }
#pragma unroll
    for (int t2 = 0; t2 < 8; t2++) {
        const short* bw = W2s + (t2 * 8 + cg * 2) * 512 + lane * 8;
        s16x8 b0  = *(const s16x8*)bw;
        s16x8 b1v = *(const s16x8*)(bw + 512);
#pragma unroll
        for (int mt = 0; mt < 4; mt++) {
            int e  = eh * 64 + mt * 16 + m;
            int sl = (t2 * 4 + q) ^ (e & 31);
            s16x8 a = *(const s16x8*)(smem + 8192 + e * 512 + sl * 16);
            acc2[mt][0] = MFMA(a, b0, acc2[mt][0]);
            acc2[mt][1] = MFMA(a, b1v, acc2[mt][1]);
        }
    }
    __syncthreads();      // h (and eattr) dead -> mbuf may alias

    // ---- messages -> mbuf (b2 pre-folded into agg by k_scanc) ----
    {
        float (*mbuf)[132] = (float (*)[132])smem;
#pragma unroll
        for (int mt = 0; mt < 4; mt++)
#pragma unroll
            for (int r = 0; r < 4; r++) {
                int edge = eh * 64 + mt * 16 + q * 4 + r;
                mbuf[edge][cg * 32 + m]      = acc2[mt][0][r];
                mbuf[edge][cg * 32 + 16 + m] = acc2[mt][1][r];
            }
    }
    __syncthreads();

    // ---- segment-reduce 128 sorted rows (quarters of 32; atomics fix seams) ----
    {
        float (*mbuf)[132] = (float (*)[132])smem;
        const int qtr = tid >> 7, cc = tid & 127;
        float s = 0.f;
        int prev = dst_s[qtr * 32];
        for (int row = qtr * 32; row < qtr * 32 + 32; row++) {
            int dcur = dst_s[row];
            if (dcur != prev) {
                __hip_atomic_fetch_add(agg + (long)prev * D + cc, s,
                                       __ATOMIC_RELAXED, __HIP_MEMORY_SCOPE_AGENT);
                s = 0.f; prev = dcur;
            }
            s += mbuf[row][cc];
        }
        __hip_atomic_fetch_add(agg + (long)prev * D + cc, s,
                               __ATOMIC_RELAXED, __HIP_MEMORY_SCOPE_AGENT);
    }
}

// ---- node MLP: quad-h layout (U2s K-permuted) ----
__global__ __launch_bounds__(512, 4)
void k_node(const short* __restrict__ xb, const float* __restrict__ agg,
            const short* __restrict__ U1s, const float* __restrict__ b1,
            const short* __restrict__ U2s, const float* __restrict__ b2,
            float* __restrict__ out) {
    __shared__ char smem[65536];     // A: 8 x [128 rows][64B]; h quad aliases
    const int tid  = threadIdx.x;
    const int lane = tid & 63;
    const int w    = tid >> 6;
    const int eh   = w >> 2;
    const int cg   = w & 3;
    const int m    = lane & 15;
    const int q    = lane >> 4;
    const int r0   = blockIdx.x * 128;

    {
        int rowl = w * 16 + (lane >> 2);
        int grow = r0 + rowl;
        int gc   = grow < NN ? grow : 0;
        int kqs  = (lane & 3) ^ ((lane >> 3) & 3);
        const char* gx = (const char*)xb + (long)gc * 256 + kqs * 16;
#pragma unroll
        for (int t = 0; t < 4; t++)
            gll16(gx + t * 64, smem + t * 8192 + w * 1024);
        const float* ga = agg + (long)gc * D + kqs * 8;
#pragma unroll
        for (int t = 0; t < 4; t++) {
            f32x4 a0 = *(const f32x4*)(ga + t * 32);
            f32x4 a1 = *(const f32x4*)(ga + t * 32 + 4);
            s16x8 v;
#pragma unroll
            for (int j = 0; j < 4; j++) { v[j] = f2bf(a0[j]); v[4 + j] = f2bf(a1[j]); }
            *(s16x8*)(smem + (4 + t) * 8192 + w * 1024 + lane * 16) = v;
        }
    }
    __syncthreads();

    const int rdoff = m * 64 + ((q ^ ((m >> 1) & 3)) << 4);

    f32x4 acc[4][4];
#pragma unroll
    for (int mt = 0; mt < 4; mt++)
#pragma unroll
        for (int n = 0; n < 4; n++) acc[mt][n] = (f32x4){0.f, 0.f, 0.f, 0.f};

#pragma unroll
    for (int t = 0; t < 8; t++) {
        s16x8 b[4];
        const short* bw = U1s + (t * 16 + cg * 4) * 512 + lane * 8;
#pragma unroll
        for (int n = 0; n < 4; n++) b[n] = *(const s16x8*)(bw + n * 512);
#pragma unroll
        for (int mt = 0; mt < 4; mt++) {
            s16x8 a = *(const s16x8*)(smem + t * 8192 + (eh * 4 + mt) * 1024 + rdoff);
#pragma unroll
            for (int n = 0; n < 4; n++) acc[mt][n] = MFMA(a, b[n], acc[mt][n]);
        }
    }
    __syncthreads();      // all A-reads done -> h quad overwrites A

    {
        char* hbase = smem;
        const int s0   = (cg * 16 + m) >> 1;
        const int half = (m & 1) * 8;
        float b1c[4];
#pragma unroll
        for (int n = 0; n < 4; n++) b1c[n] = b1[cg * 64 + n * 16 + m];
#pragma unroll
        for (int mt = 0; mt < 4; mt++) {
#pragma unroll
            for (int r = 0; r < 4; r++) {
                int row = eh * 64 + mt * 16 + q * 4 + r;
                int sl  = s0 ^ (row & 31);
                s16x4 o;
#pragma unroll
                for (int n = 0; n < 4; n++) {
                    float v = acc[mt][n][r] + b1c[n];
                    o[n] = f2bf(v > 0.f ? v : 0.f);
                }
                *(s16x4*)(hbase + row * 512 + sl * 16 + half) = o;
            }
        }
    }
    __syncthreads();

    f32x4 acc2[4][2];
#pragma unroll
    for (int mt = 0; mt < 4; mt++) {
        acc2[mt][0] = (f32x4){0.f, 0.f, 0.f, 0.f};
        acc2[mt][1] = (f32x4){0.f, 0.f, 0.f, 0.f};
    }
#pragma unroll
    for (int t2 = 0; t2 < 8; t2++) {
        const short* bw = U2s + (t2 * 8 + cg * 2) * 512 + lane * 8;
        s16x8 b0  = *(const s16x8*)bw;
        s16x8 b1v = *(const s16x8*)(bw + 512);
#pragma unroll
        for (int mt = 0; mt < 4; mt++) {
            int row = eh * 64 + mt * 16 + m;
            int sl  = (t2 * 4 + q) ^ (row & 31);
            s16x8 a = *(const s16x8*)(smem + row * 512 + sl * 16);
            acc2[mt][0] = MFMA(a, b0, acc2[mt][0]);
            acc2[mt][1] = MFMA(a, b1v, acc2[mt][1]);
        }
    }

    {
        float bb0 = b2[cg * 32 + m];
        float bb1 = b2[cg * 32 + 16 + m];
#pragma unroll
        for (int mt = 0; mt < 4; mt++)
#pragma unroll
            for (int r = 0; r < 4; r++) {
                int grow = r0 + eh * 64 + mt * 16 + q * 4 + r;
                if (grow < NN) {
                    out[(long)grow * D + cg * 32 + m]      = acc2[mt][0][r] + bb0;
                    out[(long)grow * D + cg * 32 + 16 + m] = acc2[mt][1][r] + bb1;
                }
            }
    }
}

extern "C" void kernel_launch(void* const* d_in, const int* in_sizes, int n_in,
                              void* d_out, int out_size, void* d_ws, size_t ws_size,
                              hipStream_t stream) {
    const float* x     = (const float*)d_in[0];
    const int*   ei    = (const int*)d_in[1];
    const float* eattr = (const float*)d_in[2];
    const float* cong  = (const float*)d_in[3];
    const float* mW1   = (const float*)d_in[4];
    const float* mb1   = (const float*)d_in[5];
    const float* mW2   = (const float*)d_in[6];
    const float* mb2   = (const float*)d_in[7];
    const float* uW1   = (const float*)d_in[8];
    const float* ub1   = (const float*)d_in[9];
    const float* uW2   = (const float*)d_in[10];
    const float* ub2   = (const float*)d_in[11];

    char* ws = (char*)d_ws;
    float* agg    = (float*)ws;                       // 51,200,000 B
    short* xb     = (short*)(ws + 51200000);          // 25,600,000 B
    short* W1s    = (short*)(ws + 76800000);          //    163,840 B
    short* W2s    = (short*)(ws + 76963840);          //     65,536 B
    short* U1s    = (short*)(ws + 77029376);          //    131,072 B
    short* U2s    = (short*)(ws + 77160448);          //     65,536 B
    int*   cnt    = (int*)(ws + 77225984);            //    400,000 B (cursor after scan)
    unsigned long long* chain = (unsigned long long*)(ws + 77625984);  // 1,024 B
    int*   perm   = (int*)(ws + 77627008);            //  6,400,000 B
    int2*  srcdst = (int2*)(ws + 84027008);           // 12,800,000 B
    short* yd     = (short*)(ws + 96827008);          // 51,200,000 B
    short* ys     = (short*)(ws + 148027008);         // 51,200,000 B (total ~199.2 MB)

    // one memset covers cnt + chain (contiguous)
    hipMemsetAsync(cnt, 0, 401024, stream);

    // fused cvt | hist | swz (W2/U2 K-permuted for quad-h layer 2)
    k_prep<<<19582, 256, 0, stream>>>(x, xb, ei, cnt,
                                      mW1, W1s, mW2, W2s, uW1, U1s, uW2, U2s);

    // per-node linear parts (b1 folded into ys)
    k_pre<<<(NN + 127) / 128, 512, 0, stream>>>(xb, W1s, mb1, ys, yd);

    // scan + fused agg init (agg[d][c] = deg(d)*b2[c])
    int nb = (NN + 1023) / 1024;   // 98
    k_scanc<<<nb, 1024, 0, stream>>>(cnt, chain, mb2, agg, NN);

    k_perm<<<(E_TOTAL + 255) / 256, 256, 0, stream>>>(ei, cnt, perm, srcdst);

    // 128 sorted edges per 512-thread block (8 waves, 64x64 tiles)
    k_edge<<<E_TOTAL / 128, 512, 0, stream>>>(perm, srcdst, ys, yd, eattr, cong,
                                              W1s, W2s, agg);
    // 128 rows per 512-thread block
    k_node<<<(NN + 127) / 128, 512, 0, stream>>>(xb, agg, U1s, ub1, U2s, ub2,
                                                 (float*)d_out);
}

// Round 13
// 904.855 us; speedup vs baseline: 1.0302x; 1.0302x over previous
//
#include <hip/hip_runtime.h>

#define E_TOTAL 1600000
#define NN 100000
#define D 128      // node dim
#define ED 32      // edge dim
#define H 256      // hidden dim

typedef __attribute__((ext_vector_type(8))) short s16x8;   // 8 bf16 (one MFMA A/B frag)
typedef __attribute__((ext_vector_type(4))) short s16x4;
typedef __attribute__((ext_vector_type(4))) float f32x4;

#define MFMA(a, b, c) __builtin_amdgcn_mfma_f32_16x16x32_bf16((a), (b), (c), 0, 0, 0)

__device__ __forceinline__ short f2bf(float f) {
    unsigned u = __builtin_bit_cast(unsigned, f);
    u += 0x7fffu + ((u >> 16) & 1u);   // round-to-nearest-even
    return (short)(u >> 16);
}
__device__ __forceinline__ float bf2f(short s) {
    return __builtin_bit_cast(float, ((unsigned)(unsigned short)s) << 16);
}
// HW packed f32x2 -> bf16x2 (RNE), gfx950. low16 <- a, high16 <- b.
__device__ __forceinline__ unsigned cvtpk(float a, float b) {
    unsigned r;
    asm("v_cvt_pk_bf16_f32 %0, %1, %2" : "=v"(r) : "v"(a), "v"(b));
    return r;
}
union u_s16x4 { s16x4 v; unsigned u[2]; };
union u_s16x8 { s16x8 v; unsigned u[4]; };

// async global->LDS, 16B per lane; LDS dest is wave-uniform base (HW adds lane*16)
__device__ __forceinline__ void gll16(const void* g, void* l) {
    __builtin_amdgcn_global_load_lds(
        (const __attribute__((address_space(1))) void*)g,
        (__attribute__((address_space(3))) void*)l, 16, 0, 0);
}

// ---- fused prep: x->bf16 cvt | dst histogram | weight swizzles ----
__device__ __forceinline__ void swz_one(const float* __restrict__ W,
                                        short* __restrict__ out,
                                        int K, int N, int idx) {
    int j    = idx & 7;
    int lane = (idx >> 3) & 63;
    int rest = idx >> 9;
    int NT   = N >> 4;
    int nt   = rest % NT;
    int t    = rest / NT;
    int k    = t * 32 + (lane >> 4) * 8 + j;
    int col  = nt * 16 + (lane & 15);
    out[idx] = f2bf((k < K) ? W[k * N + col] : 0.f);
}

// K-permuted variant for layer-2 weights (quad-h layout):
// pi(p) = (p>>6)*64 + (p&3)*16 + ((p>>2)&15)
__device__ __forceinline__ void swz_kp(const float* __restrict__ W,
                                       short* __restrict__ out, int N, int idx) {
    int j    = idx & 7;
    int lane = (idx >> 3) & 63;
    int rest = idx >> 9;
    int NT   = N >> 4;
    int nt   = rest % NT;
    int t    = rest / NT;
    int p    = t * 32 + (lane >> 4) * 8 + j;
    int k    = (p >> 6) * 64 + (p & 3) * 16 + ((p >> 2) & 15);
    int col  = nt * 16 + (lane & 15);
    out[idx] = f2bf(W[k * N + col]);
}

__global__ void k_prep(const float* __restrict__ x, short* __restrict__ xb,
                       const int* __restrict__ ei, int* __restrict__ cnt,
                       const float* __restrict__ mW1, short* __restrict__ W1s,
                       const float* __restrict__ mW2, short* __restrict__ W2s,
                       const float* __restrict__ uW1, short* __restrict__ U1s,
                       const float* __restrict__ uW2, short* __restrict__ U2s) {
    const int b = blockIdx.x;
    if (b < 12500) {                       // cvt x -> bf16 (packed HW cvt)
        int i = (b * 256 + threadIdx.x) * 4;
        if (i >= NN * D) return;
        f32x4 v = *(const f32x4*)(x + i);
        u_s16x4 o;
        o.u[0] = cvtpk(v[0], v[1]);
        o.u[1] = cvtpk(v[2], v[3]);
        *(s16x4*)(xb + i) = o.v;
    } else if (b < 18750) {                // dst histogram
        int e = (b - 12500) * 256 + threadIdx.x;
        if (e < E_TOTAL) atomicAdd(&cnt[ei[E_TOTAL + e]], 1);
    } else {                               // 4 weight swizzles (W2/U2 K-permuted)
        int idx = (b - 18750) * 256 + threadIdx.x;
        if (idx < 81920) { swz_one(mW1, W1s, 289, 256, idx); return; }
        idx -= 81920;
        if (idx < 32768) { swz_kp(mW2, W2s, 128, idx); return; }
        idx -= 32768;
        if (idx < 65536) { swz_one(uW1, U1s, 256, 256, idx); return; }
        idx -= 65536;
        if (idx < 32768) { swz_kp(uW2, U2s, 128, idx); }
    }
}

// ---- single-kernel scan: per-block scan + decoupled lookback (scan only) ----
__global__ void k_scanc(int* __restrict__ cnt, unsigned long long* __restrict__ chain,
                        int n) {
    __shared__ int wsum[16];
    __shared__ int woff[16];
    __shared__ int carry_s;
    const int tid = threadIdx.x, lane = tid & 63, wv = tid >> 6;
    int i = blockIdx.x * 1024 + tid;
    int v = (i < n) ? cnt[i] : 0;
    int s = v;
#pragma unroll
    for (int off = 1; off < 64; off <<= 1) {
        int u = __shfl_up(s, off, 64);
        if (lane >= off) s += u;
    }
    if (lane == 63) wsum[wv] = s;
    __syncthreads();
    if (wv == 0 && lane < 16) {
        int t = wsum[lane];
        int sc = t;
#pragma unroll
        for (int off = 1; off < 16; off <<= 1) {
            int u = __shfl_up(sc, off, 16);
            if (lane >= off) sc += u;
        }
        woff[lane] = sc - t;
    }
    __syncthreads();
    int excl = (s - v) + woff[wv];
    if (tid == 1023) {
        int btot = excl + v;
        __hip_atomic_store(&chain[blockIdx.x], (1ull << 32) | (unsigned)btot,
                           __ATOMIC_RELAXED, __HIP_MEMORY_SCOPE_AGENT);
        int pfx = 0;
        for (int j = (int)blockIdx.x - 1; j >= 0; --j) {
            unsigned long long e;
            do {
                e = __hip_atomic_load(&chain[j], __ATOMIC_RELAXED,
                                      __HIP_MEMORY_SCOPE_AGENT);
            } while ((e >> 32) == 0);
            pfx += (int)(unsigned)e;
            if ((e >> 32) == 2) break;
        }
        __hip_atomic_store(&chain[blockIdx.x], (2ull << 32) | (unsigned)(pfx + btot),
                           __ATOMIC_RELAXED, __HIP_MEMORY_SCOPE_AGENT);
        carry_s = pfx;
    }
    __syncthreads();
    if (i < n) cnt[i] = excl + carry_s;
}

// ---- agg init: agg[d][c] = deg(d) * b2[c]  (fully parallel streamer) ----
__global__ void k_agginit(const int* __restrict__ cnt, const float* __restrict__ b2,
                          float* __restrict__ agg) {
    int i4 = (blockIdx.x * 256 + threadIdx.x) * 4;
    if (i4 >= NN * D) return;
    int node  = i4 >> 7;
    int c     = i4 & 127;
    int start = cnt[node];
    int end   = (node < NN - 1) ? cnt[node + 1] : E_TOTAL;
    float deg = (float)(end - start);
    f32x4 bv = *(const f32x4*)(b2 + c);
    f32x4 o;
#pragma unroll
    for (int j = 0; j < 4; j++) o[j] = deg * bv[j];
    *(f32x4*)(agg + i4) = o;
}

// ---- sort prep: scatter edges into dst-sorted order ----
__global__ void k_perm(const int* __restrict__ ei, int* __restrict__ cursor,
                       int* __restrict__ perm, int2* __restrict__ srcdst) {
    int e = blockIdx.x * blockDim.x + threadIdx.x;
    if (e >= E_TOTAL) return;
    int s = ei[e], d = ei[E_TOTAL + e];
    int pos = atomicAdd(&cursor[d], 1);
    perm[pos] = e;
    srcdst[pos] = make_int2(s, d);
}

// ---- per-node precompute ----
// ys[node] = x@W1[:128] + b1 + cong[node]*W1[288,:]   (cong is src-indexed!)
// yd[node] = x@W1[128:256]
// Quad C-fragment layout: y[node*256 + (cg*16+m)*4 + n] = col (cg*64+n*16+m).
__global__ __launch_bounds__(512, 4)
void k_pre(const short* __restrict__ xb, const short* __restrict__ W1s,
           const float* __restrict__ b1, const float* __restrict__ cong,
           const float* __restrict__ w288, short* __restrict__ ys,
           short* __restrict__ yd) {
    __shared__ char smem[32768];     // x: 4 chunks x [128 rows][64B], swizzled
    const int tid  = threadIdx.x;
    const int lane = tid & 63;
    const int w    = tid >> 6;
    const int eh   = w >> 2;
    const int cg   = w & 3;
    const int m    = lane & 15;
    const int q    = lane >> 4;
    const int r0   = blockIdx.x * 128;

    {
        int rowl = w * 16 + (lane >> 2);
        int grow = r0 + rowl;
        int gc   = grow < NN ? grow : 0;
        int kqs  = (lane & 3) ^ ((lane >> 3) & 3);
        const char* gx = (const char*)xb + (long)gc * 256 + kqs * 16;
#pragma unroll
        for (int t = 0; t < 4; t++)
            gll16(gx + t * 64, smem + t * 8192 + w * 1024);
    }
    __syncthreads();

    const int rdoff = m * 64 + ((q ^ ((m >> 1) & 3)) << 4);

    float b1c[4], w288c[4];
#pragma unroll
    for (int n = 0; n < 4; n++) {
        b1c[n]   = b1[cg * 64 + n * 16 + m];
        w288c[n] = w288[cg * 64 + n * 16 + m];
    }

#pragma unroll
    for (int pass = 0; pass < 2; pass++) {   // 0: ys (W1 chunks 0..3), 1: yd (4..7)
        f32x4 acc[4][4];
#pragma unroll
        for (int mt = 0; mt < 4; mt++)
#pragma unroll
            for (int n = 0; n < 4; n++) acc[mt][n] = (f32x4){0.f, 0.f, 0.f, 0.f};
#pragma unroll
        for (int t = 0; t < 4; t++) {
            s16x8 b[4];
            const short* bw = W1s + ((pass * 4 + t) * 16 + cg * 4) * 512 + lane * 8;
#pragma unroll
            for (int n = 0; n < 4; n++) b[n] = *(const s16x8*)(bw + n * 512);
#pragma unroll
            for (int mt = 0; mt < 4; mt++) {
                s16x8 a = *(const s16x8*)(smem + t * 8192 + (eh * 4 + mt) * 1024 + rdoff);
#pragma unroll
                for (int n = 0; n < 4; n++) acc[mt][n] = MFMA(a, b[n], acc[mt][n]);
            }
        }
        short* out = pass ? yd : ys;
#pragma unroll
        for (int mt = 0; mt < 4; mt++)
#pragma unroll
            for (int r = 0; r < 4; r++) {
                int grow = r0 + eh * 64 + mt * 16 + q * 4 + r;
                if (grow < NN) {
                    float vv[4];
                    if (pass == 0) {
                        float cv = cong[grow];     // broadcast across the 16 lanes
#pragma unroll
                        for (int n = 0; n < 4; n++)
                            vv[n] = acc[mt][n][r] + b1c[n] + cv * w288c[n];
                    } else {
#pragma unroll
                        for (int n = 0; n < 4; n++) vv[n] = acc[mt][n][r];
                    }
                    u_s16x4 o;
                    o.u[0] = cvtpk(vv[0], vv[1]);
                    o.u[1] = cvtpk(vv[2], vv[3]);
                    *(s16x4*)(out + (long)grow * 256 + (cg * 16 + m) * 4) = o.v;
                }
            }
    }
}

// ---- edge MLP + segment-reduced scatter-add: quad-h, cong folded into ys ----
// Layer 1 = single eattr k-chunk (16 MFMA/wave). h = relu(acc + ys[src] +
// yd[dst]) packed with v_cvt_pk_bf16_f32 (2 insts per s16x4). Layer 2 reads
// quad-h physical k-slots (W2s K-permuted), 64 MFMA/wave.
__global__ __launch_bounds__(512, 4)
void k_edge(const int* __restrict__ perm, const int2* __restrict__ srcdst,
            const short* __restrict__ ys, const short* __restrict__ yd,
            const float* __restrict__ eattr,
            const short* __restrict__ W1s, const short* __restrict__ W2s,
            float* __restrict__ agg) {
    __shared__ char smem[73728];     // eattr chunk [0,8K); h quad [8K,72K); mbuf aliases
    __shared__ int dst_s[128];
    __shared__ int src_s[128];

    const int tid  = threadIdx.x;
    const int lane = tid & 63;
    const int w    = tid >> 6;       // wave 0..7
    const int eh   = w >> 2;         // edge half: rows [eh*64, +64)
    const int cg   = w & 3;          // col group: l1 cols [cg*64,+64), l2 [cg*32,+32)
    const int m    = lane & 15;
    const int q    = lane >> 4;
    const int p0b  = blockIdx.x * 128;

    // ---- stage eattr chunk (swizzled) + edge metadata ----
    {
        int edge = w * 16 + (lane >> 2);
        int kqs  = (lane & 3) ^ ((lane >> 3) & 3);
        int ea = perm[p0b + edge];
        const float* ge = eattr + (long)ea * ED + kqs * 8;
        f32x4 e0 = *(const f32x4*)ge, e1 = *(const f32x4*)(ge + 4);
        u_s16x8 ev;
        ev.u[0] = cvtpk(e0[0], e0[1]);
        ev.u[1] = cvtpk(e0[2], e0[3]);
        ev.u[2] = cvtpk(e1[0], e1[1]);
        ev.u[3] = cvtpk(e1[2], e1[3]);
        *(s16x8*)(smem + w * 1024 + lane * 16) = ev.v;
        if (tid < 128) {
            int2 sd2 = srcdst[p0b + tid];
            dst_s[tid] = sd2.y;
            src_s[tid] = sd2.x;
        }
    }
    __syncthreads();

    const int rdoff = m * 64 + ((q ^ ((m >> 1) & 3)) << 4);   // conflict-free A-read

    // ---- layer 1: single eattr k-chunk (W1 chunk 8); 64 edges x 64 cols ----
    f32x4 acc[4][4];
#pragma unroll
    for (int mt = 0; mt < 4; mt++)
#pragma unroll
        for (int n = 0; n < 4; n++) acc[mt][n] = (f32x4){0.f, 0.f, 0.f, 0.f};
    {
        s16x8 b[4];
        const short* bw = W1s + (8 * 16 + cg * 4) * 512 + lane * 8;
#pragma unroll
        for (int n = 0; n < 4; n++) b[n] = *(const s16x8*)(bw + n * 512);
#pragma unroll
        for (int mt = 0; mt < 4; mt++) {
            s16x8 a = *(const s16x8*)(smem + (eh * 4 + mt) * 1024 + rdoff);
#pragma unroll
            for (int n = 0; n < 4; n++) acc[mt][n] = MFMA(a, b[n], acc[mt][n]);
        }
    }

    // ---- h-write: relu(acc + ys[src] + yd[dst]) -> quad layout, b64 stores ----
    {
        char* hbase = smem + 8192;
        const int qoff = (cg * 16 + m) * 4;
        const int s0   = (cg * 16 + m) >> 1;      // 16B slot index (pre-XOR)
        const int half = (m & 1) * 8;             // byte offset within slot
#pragma unroll
        for (int mt = 0; mt < 4; mt++) {
            s16x4 ysv[4], ydv[4];
#pragma unroll
            for (int r = 0; r < 4; r++) {          // batched loads, 4-deep pipeline
                int e = eh * 64 + mt * 16 + q * 4 + r;
                ysv[r] = *(const s16x4*)(ys + (long)src_s[e] * 256 + qoff);
                ydv[r] = *(const s16x4*)(yd + (long)dst_s[e] * 256 + qoff);
            }
#pragma unroll
            for (int r = 0; r < 4; r++) {
                int e = eh * 64 + mt * 16 + q * 4 + r;
                int sl = s0 ^ (e & 31);
                float vv[4];
#pragma unroll
                for (int n = 0; n < 4; n++) {
                    float v = acc[mt][n][r] + bf2f(ysv[r][n]) + bf2f(ydv[r][n]);
                    vv[n] = v > 0.f ? v : 0.f;
                }
                u_s16x4 o;
                o.u[0] = cvtpk(vv[0], vv[1]);
                o.u[1] = cvtpk(vv[2], vv[3]);
                *(s16x4*)(hbase + e * 512 + sl * 16 + half) = o.v;
            }
        }
    }
    __syncthreads();

    // ---- layer 2: K=256 (physical k-slots); 64 edges x 32 cols per wave ----
    f32x4 acc2[4][2];
#pragma unroll
    for (int mt = 0; mt < 4; mt++) {
        acc2[mt][0] = (f32x4){0.f, 0.f, 0.f, 0.f};
        acc2[mt][1] = (f32x4){0.f, 0.f, 0.f, 0.f};
    }
#pragma unroll
    for (int t2 = 0; t2 < 8; t2++) {
        const short* bw = W2s + (t2 * 8 + cg * 2) * 512 + lane * 8;
        s16x8 b0  = *(const s16x8*)bw;
        s16x8 b1v = *(const s16x8*)(bw + 512);
#pragma unroll
        for (int mt = 0; mt < 4; mt++) {
            int e  = eh * 64 + mt * 16 + m;
            int sl = (t2 * 4 + q) ^ (e & 31);
            s16x8 a = *(const s16x8*)(smem + 8192 + e * 512 + sl * 16);
            acc2[mt][0] = MFMA(a, b0, acc2[mt][0]);
            acc2[mt][1] = MFMA(a, b1v, acc2[mt][1]);
        }
    }
    __syncthreads();      // h (and eattr) dead -> mbuf may alias

    // ---- messages -> mbuf (b2 pre-folded into agg by k_agginit) ----
    {
        float (*mbuf)[132] = (float (*)[132])smem;
#pragma unroll
        for (int mt = 0; mt < 4; mt++)
#pragma unroll
            for (int r = 0; r < 4; r++) {
                int edge = eh * 64 + mt * 16 + q * 4 + r;
                mbuf[edge][cg * 32 + m]      = acc2[mt][0][r];
                mbuf[edge][cg * 32 + 16 + m] = acc2[mt][1][r];
            }
    }
    __syncthreads();

    // ---- segment-reduce 128 sorted rows (quarters of 32; atomics fix seams) ----
    {
        float (*mbuf)[132] = (float (*)[132])smem;
        const int qtr = tid >> 7, cc = tid & 127;
        float s = 0.f;
        int prev = dst_s[qtr * 32];
        for (int row = qtr * 32; row < qtr * 32 + 32; row++) {
            int dcur = dst_s[row];
            if (dcur != prev) {
                __hip_atomic_fetch_add(agg + (long)prev * D + cc, s,
                                       __ATOMIC_RELAXED, __HIP_MEMORY_SCOPE_AGENT);
                s = 0.f; prev = dcur;
            }
            s += mbuf[row][cc];
        }
        __hip_atomic_fetch_add(agg + (long)prev * D + cc, s,
                               __ATOMIC_RELAXED, __HIP_MEMORY_SCOPE_AGENT);
    }
}

// ---- node MLP: quad-h layout (U2s K-permuted), packed cvt ----
__global__ __launch_bounds__(512, 4)
void k_node(const short* __restrict__ xb, const float* __restrict__ agg,
            const short* __restrict__ U1s, const float* __restrict__ b1,
            const short* __restrict__ U2s, const float* __restrict__ b2,
            float* __restrict__ out) {
    __shared__ char smem[65536];     // A: 8 x [128 rows][64B]; h quad aliases
    const int tid  = threadIdx.x;
    const int lane = tid & 63;
    const int w    = tid >> 6;
    const int eh   = w >> 2;
    const int cg   = w & 3;
    const int m    = lane & 15;
    const int q    = lane >> 4;
    const int r0   = blockIdx.x * 128;

    {
        int rowl = w * 16 + (lane >> 2);
        int grow = r0 + rowl;
        int gc   = grow < NN ? grow : 0;
        int kqs  = (lane & 3) ^ ((lane >> 3) & 3);
        const char* gx = (const char*)xb + (long)gc * 256 + kqs * 16;
#pragma unroll
        for (int t = 0; t < 4; t++)
            gll16(gx + t * 64, smem + t * 8192 + w * 1024);
        const float* ga = agg + (long)gc * D + kqs * 8;
#pragma unroll
        for (int t = 0; t < 4; t++) {
            f32x4 a0 = *(const f32x4*)(ga + t * 32);
            f32x4 a1 = *(const f32x4*)(ga + t * 32 + 4);
            u_s16x8 v;
            v.u[0] = cvtpk(a0[0], a0[1]);
            v.u[1] = cvtpk(a0[2], a0[3]);
            v.u[2] = cvtpk(a1[0], a1[1]);
            v.u[3] = cvtpk(a1[2], a1[3]);
            *(s16x8*)(smem + (4 + t) * 8192 + w * 1024 + lane * 16) = v.v;
        }
    }
    __syncthreads();

    const int rdoff = m * 64 + ((q ^ ((m >> 1) & 3)) << 4);

    f32x4 acc[4][4];
#pragma unroll
    for (int mt = 0; mt < 4; mt++)
#pragma unroll
        for (int n = 0; n < 4; n++) acc[mt][n] = (f32x4){0.f, 0.f, 0.f, 0.f};

#pragma unroll
    for (int t = 0; t < 8; t++) {
        s16x8 b[4];
        const short* bw = U1s + (t * 16 + cg * 4) * 512 + lane * 8;
#pragma unroll
        for (int n = 0; n < 4; n++) b[n] = *(const s16x8*)(bw + n * 512);
#pragma unroll
        for (int mt = 0; mt < 4; mt++) {
            s16x8 a = *(const s16x8*)(smem + t * 8192 + (eh * 4 + mt) * 1024 + rdoff);
#pragma unroll
            for (int n = 0; n < 4; n++) acc[mt][n] = MFMA(a, b[n], acc[mt][n]);
        }
    }
    __syncthreads();      // all A-reads done -> h quad overwrites A

    {
        char* hbase = smem;
        const int s0   = (cg * 16 + m) >> 1;
        const int half = (m & 1) * 8;
        float b1c[4];
#pragma unroll
        for (int n = 0; n < 4; n++) b1c[n] = b1[cg * 64 + n * 16 + m];
#pragma unroll
        for (int mt = 0; mt < 4; mt++) {
#pragma unroll
            for (int r = 0; r < 4; r++) {
                int row = mt * 16 + q * 4 + r + eh * 64;
                int sl  = s0 ^ (row & 31);
                float vv[4];
#pragma unroll
                for (int n = 0; n < 4; n++) {
                    float v = acc[mt][n][r] + b1c[n];
                    vv[n] = v > 0.f ? v : 0.f;
                }
                u_s16x4 o;
                o.u[0] = cvtpk(vv[0], vv[1]);
                o.u[1] = cvtpk(vv[2], vv[3]);
                *(s16x4*)(hbase + row * 512 + sl * 16 + half) = o.v;
            }
        }
    }
    __syncthreads();

    f32x4 acc2[4][2];
#pragma unroll
    for (int mt = 0; mt < 4; mt++) {
        acc2[mt][0] = (f32x4){0.f, 0.f, 0.f, 0.f};
        acc2[mt][1] = (f32x4){0.f, 0.f, 0.f, 0.f};
    }
#pragma unroll
    for (int t2 = 0; t2 < 8; t2++) {
        const short* bw = U2s + (t2 * 8 + cg * 2) * 512 + lane * 8;
        s16x8 b0  = *(const s16x8*)bw;
        s16x8 b1v = *(const s16x8*)(bw + 512);
#pragma unroll
        for (int mt = 0; mt < 4; mt++) {
            int row = eh * 64 + mt * 16 + m;
            int sl  = (t2 * 4 + q) ^ (row & 31);
            s16x8 a = *(const s16x8*)(smem + row * 512 + sl * 16);
            acc2[mt][0] = MFMA(a, b0, acc2[mt][0]);
            acc2[mt][1] = MFMA(a, b1v, acc2[mt][1]);
        }
    }

    {
        float bb0 = b2[cg * 32 + m];
        float bb1 = b2[cg * 32 + 16 + m];
#pragma unroll
        for (int mt = 0; mt < 4; mt++)
#pragma unroll
            for (int r = 0; r < 4; r++) {
                int grow = r0 + eh * 64 + mt * 16 + q * 4 + r;
                if (grow < NN) {
                    out[(long)grow * D + cg * 32 + m]      = acc2[mt][0][r] + bb0;
                    out[(long)grow * D + cg * 32 + 16 + m] = acc2[mt][1][r] + bb1;
                }
            }
    }
}

extern "C" void kernel_launch(void* const* d_in, const int* in_sizes, int n_in,
                              void* d_out, int out_size, void* d_ws, size_t ws_size,
                              hipStream_t stream) {
    const float* x     = (const float*)d_in[0];
    const int*   ei    = (const int*)d_in[1];
    const float* eattr = (const float*)d_in[2];
    const float* cong  = (const float*)d_in[3];
    const float* mW1   = (const float*)d_in[4];
    const float* mb1   = (const float*)d_in[5];
    const float* mW2   = (const float*)d_in[6];
    const float* mb2   = (const float*)d_in[7];
    const float* uW1   = (const float*)d_in[8];
    const float* ub1   = (const float*)d_in[9];
    const float* uW2   = (const float*)d_in[10];
    const float* ub2   = (const float*)d_in[11];

    char* ws = (char*)d_ws;
    float* agg    = (float*)ws;                       // 51,200,000 B
    short* xb     = (short*)(ws + 51200000);          // 25,600,000 B
    short* W1s    = (short*)(ws + 76800000);          //    163,840 B
    short* W2s    = (short*)(ws + 76963840);          //     65,536 B
    short* U1s    = (short*)(ws + 77029376);          //    131,072 B
    short* U2s    = (short*)(ws + 77160448);          //     65,536 B
    int*   cnt    = (int*)(ws + 77225984);            //    400,000 B (cursor after scan)
    unsigned long long* chain = (unsigned long long*)(ws + 77625984);  // 1,024 B
    int*   perm   = (int*)(ws + 77627008);            //  6,400,000 B
    int2*  srcdst = (int2*)(ws + 84027008);           // 12,800,000 B
    short* yd     = (short*)(ws + 96827008);          // 51,200,000 B
    short* ys     = (short*)(ws + 148027008);         // 51,200,000 B (total ~199.2 MB)

    // one memset covers cnt + chain (contiguous)
    hipMemsetAsync(cnt, 0, 401024, stream);

    // fused cvt | hist | swz (W2/U2 K-permuted for quad-h layer 2)
    k_prep<<<19582, 256, 0, stream>>>(x, xb, ei, cnt,
                                      mW1, W1s, mW2, W2s, uW1, U1s, uW2, U2s);

    // per-node linear parts (b1 + cong*W1[288,:] folded into ys)
    k_pre<<<(NN + 127) / 128, 512, 0, stream>>>(xb, W1s, mb1, cong,
                                                mW1 + 288 * 256, ys, yd);

    // scan (decoupled lookback, single kernel)
    int nb = (NN + 1023) / 1024;   // 98
    k_scanc<<<nb, 1024, 0, stream>>>(cnt, chain, NN);

    // agg[d][c] = deg(d)*b2[c]  (parallel streamer; folds per-edge b2 add)
    k_agginit<<<12500, 256, 0, stream>>>(cnt, mb2, agg);

    k_perm<<<(E_TOTAL + 255) / 256, 256, 0, stream>>>(ei, cnt, perm, srcdst);

    // 128 sorted edges per 512-thread block (8 waves, 64x64 tiles)
    k_edge<<<E_TOTAL / 128, 512, 0, stream>>>(perm, srcdst, ys, yd, eattr,
                                              W1s, W2s, agg);
    // 128 rows per 512-thread block
    k_node<<<(NN + 127) / 128, 512, 0, stream>>>(xb, agg, U1s, ub1, U2s, ub2,
                                                 (float*)d_out);
}